// Round 13
// baseline (54.016 us; speedup 1.0000x reference)
//
#include <hip/hip_runtime.h>
#include <hip/hip_bf16.h>

#define NBATCH 4
#define NNODE  20000
#define NF     128
#define NK     16
#define NROWS  (NBATCH * NNODE)   // 80000
#define NBLK_G 1250               // fused blocks, 64 rows each
#define WTF_BYTES 65536           // frag table: 2 halves x 8t x 4s x 64lane x 16B
#define BIAS_OFF  WTF_BYTES
#define Y_OFF     (WTF_BYTES + 1024)   // fp8 x copy, fragment-interleaved (10.24 MB)

typedef __attribute__((ext_vector_type(8))) short bf16x8_t;
typedef __attribute__((ext_vector_type(4))) float f32x4_t;
typedef __attribute__((ext_vector_type(2))) float f32x2_t;

__device__ __forceinline__ unsigned int f2bf(float f) {
  unsigned int u = __float_as_uint(f);
  u += 0x7fffu + ((u >> 16) & 1u);
  return u >> 16;
}

__device__ __forceinline__ int xcd_swz_g(int orig) {
  // bijective XCD-chunked swizzle, nwg=1250: q=156, r=2
  const int xcd = orig & 7, i = orig >> 3;
  const int q = NBLK_G / 8, r = NBLK_G % 8;
  return (xcd < r ? xcd * (q + 1) : r * (q + 1) + (xcd - r) * q) + i;
}

__device__ __forceinline__ void stage16(const void* g, void* l) {
  __builtin_amdgcn_global_load_lds(
      (const __attribute__((address_space(1))) unsigned int*)g,
      (__attribute__((address_space(3))) unsigned int*)l, 16, 0, 0);
}

// ---------------- K1: prep (merged) --------------------------------------
// bid <  2048 : x -> fp8 copy, fragment-interleaved (f=s*32+q*8+j -> q*32+s*8+j)
// bid >= 2048 : weight frag table, half 0 = Ws (k-steps 0..3), half 1 = Wn
// bid == 2064 : bias sum
__global__ __launch_bounds__(256) void sage_prep(
    const float* __restrict__ x, const float* __restrict__ Ws,
    const float* __restrict__ bs, const float* __restrict__ Wn,
    const float* __restrict__ bn, unsigned char* __restrict__ ws)
{
  const int bid = blockIdx.x, tid = threadIdx.x;
  if (bid < 2048) {
    unsigned char* yp = ws + Y_OFF;
    const int total = NROWS * 32;   // uint (4-feature) chunks
    for (int c = bid * 256 + tid; c < total; c += 2048 * 256) {
      const int r = c >> 5;
      const int f = (c & 31) * 4;
      const float4 v = *reinterpret_cast<const float4*>(x + (size_t)r * NF + f);
      int p8 = __builtin_amdgcn_cvt_pk_fp8_f32(v.x, v.y, 0, false);
      p8 = __builtin_amdgcn_cvt_pk_fp8_f32(v.z, v.w, p8, true);
      const int q = (f >> 3) & 3, sp = f >> 5, j = f & 7;
      *reinterpret_cast<unsigned int*>(
          yp + (size_t)r * NF + q * 32 + sp * 8 + j) = (unsigned int)p8;
    }
    return;
  }
  if (bid == 2064) {
    if (tid < NF) ((float*)(ws + BIAS_OFF))[tid] = bs[tid] + bn[tid];
    return;
  }
  const int ft = (bid - 2048) * 256 + tid;  // 0..4095
  const int half = ft >> 11;                // 0 = Ws, 1 = Wn
  const int rem  = ft & 2047;
  const int t = rem >> 8;                   // col tile 0..7
  const int s = (rem >> 6) & 3;             // k-step within half
  const int l = rem & 63;
  const int col = t * 16 + (l & 15);
  const int k0 = s * 32 + ((l >> 4) << 3);
  const float* W = half ? Wn : Ws;
  unsigned int w[4];
#pragma unroll
  for (int jj = 0; jj < 4; ++jj) {
    const float va = W[(k0 + 2 * jj) * NF + col];
    const float vb = W[(k0 + 2 * jj + 1) * NF + col];
    w[jj] = f2bf(va) | (f2bf(vb) << 16);
  }
  *reinterpret_cast<uint4*>(ws + (size_t)ft * 16) = make_uint4(w[0], w[1], w[2], w[3]);
}

// ---------------- K2: fused gather + GEMM, 32KB LDS, direct out ----------
// operand-swapped mfma(Wfrag, bfrag): lane (fl,q) owns x-row fl and 4
// consecutive out cols (q*4+reg) per tile -> packed float4 stores.
__global__ __launch_bounds__(256) void sage_fused(
    const float* __restrict__ x, const unsigned char* __restrict__ ws,
    const int* __restrict__ adj, float* __restrict__ out)
{
  __shared__ __align__(16) unsigned char sW[32768];

  const int tid = threadIdx.x, lane = tid & 63, wid = tid >> 6;
  const int bid = xcd_swz_g(blockIdx.x);
  const int fl = lane & 15, q = lane >> 4;
  const int row0 = bid * 64;
  const int myrow = row0 + wid * 16 + fl;

  // ---- issue x loads first (oldest in vmcnt FIFO)
  const float* xr = x + (size_t)myrow * NF + q * 8;
  float4 xv[8];
#pragma unroll
  for (int s = 0; s < 4; ++s) {
    xv[2 * s]     = *reinterpret_cast<const float4*>(xr + s * 32);
    xv[2 * s + 1] = *reinterpret_cast<const float4*>(xr + s * 32 + 4);
  }
  // ---- adj indices
  const int4* a4 = reinterpret_cast<const int4*>(adj + (size_t)myrow * NK);
  const int4 t0 = a4[0], t1 = a4[1], t2 = a4[2], t3 = a4[3];
  // ---- stage Ws-half frag table (32KB) via async DMA
#pragma unroll
  for (int i = 0; i < 8; ++i) {
    const int c0 = i * 256 + wid * 64;
    stage16(ws + (size_t)(c0 + lane) * 16, sW + (size_t)c0 * 16);
  }
  __builtin_amdgcn_sched_barrier(0);

  // ---- gather + mean, fully in-register (fragment-interleaved fp8)
  bf16x8_t bm[4];
  {
    const int idx[16] = {t0.x, t0.y, t0.z, t0.w, t1.x, t1.y, t1.z, t1.w,
                         t2.x, t2.y, t2.z, t2.w, t3.x, t3.y, t3.z, t3.w};
    const int b = myrow / NNODE;
    const unsigned char* yb = ws + Y_OFF + (size_t)b * NNODE * NF + q * 32;

    f32x2_t g[16];
#pragma unroll
    for (int e = 0; e < 16; ++e) g[e] = (f32x2_t){0.f, 0.f};

#define ACCW(word, base)                                                   \
    {                                                                      \
      g[(base)]     += __builtin_amdgcn_cvt_pk_f32_fp8((word), false);     \
      g[(base) + 1] += __builtin_amdgcn_cvt_pk_f32_fp8((word), true);      \
    }
#pragma unroll
    for (int n = 0; n < 16; n += 4) {
      uint4 u0a = *reinterpret_cast<const uint4*>(yb + (size_t)idx[n + 0] * NF);
      uint4 u0b = *reinterpret_cast<const uint4*>(yb + (size_t)idx[n + 0] * NF + 16);
      uint4 u1a = *reinterpret_cast<const uint4*>(yb + (size_t)idx[n + 1] * NF);
      uint4 u1b = *reinterpret_cast<const uint4*>(yb + (size_t)idx[n + 1] * NF + 16);
      uint4 u2a = *reinterpret_cast<const uint4*>(yb + (size_t)idx[n + 2] * NF);
      uint4 u2b = *reinterpret_cast<const uint4*>(yb + (size_t)idx[n + 2] * NF + 16);
      uint4 u3a = *reinterpret_cast<const uint4*>(yb + (size_t)idx[n + 3] * NF);
      uint4 u3b = *reinterpret_cast<const uint4*>(yb + (size_t)idx[n + 3] * NF + 16);
      ACCW(u0a.x, 0)  ACCW(u0a.y, 2)  ACCW(u0a.z, 4)  ACCW(u0a.w, 6)
      ACCW(u0b.x, 8)  ACCW(u0b.y, 10) ACCW(u0b.z, 12) ACCW(u0b.w, 14)
      ACCW(u1a.x, 0)  ACCW(u1a.y, 2)  ACCW(u1a.z, 4)  ACCW(u1a.w, 6)
      ACCW(u1b.x, 8)  ACCW(u1b.y, 10) ACCW(u1b.z, 12) ACCW(u1b.w, 14)
      ACCW(u2a.x, 0)  ACCW(u2a.y, 2)  ACCW(u2a.z, 4)  ACCW(u2a.w, 6)
      ACCW(u2b.x, 8)  ACCW(u2b.y, 10) ACCW(u2b.z, 12) ACCW(u2b.w, 14)
      ACCW(u3a.x, 0)  ACCW(u3a.y, 2)  ACCW(u3a.z, 4)  ACCW(u3a.w, 6)
      ACCW(u3b.x, 8)  ACCW(u3b.y, 10) ACCW(u3b.z, 12) ACCW(u3b.w, 14)
    }
#undef ACCW

    const float sc = 1.f / 16.f;
#pragma unroll
    for (int sp = 0; sp < 4; ++sp) {
      union { unsigned int u[4]; bf16x8_t v; } r;
#pragma unroll
      for (int e = 0; e < 4; ++e) {
        const f32x2_t a = g[sp * 4 + e];
        r.u[e] = f2bf(a[0] * sc) | (f2bf(a[1] * sc) << 16);
      }
      bm[sp] = r.v;
    }
  }

  // ---- convert x to bf16 B-fragments
  bf16x8_t bx[4];
#pragma unroll
  for (int s = 0; s < 4; ++s) {
    union { unsigned int u[4]; bf16x8_t v; } r;
    r.u[0] = f2bf(xv[2 * s].x) | (f2bf(xv[2 * s].y) << 16);
    r.u[1] = f2bf(xv[2 * s].z) | (f2bf(xv[2 * s].w) << 16);
    r.u[2] = f2bf(xv[2 * s + 1].x) | (f2bf(xv[2 * s + 1].y) << 16);
    r.u[3] = f2bf(xv[2 * s + 1].z) | (f2bf(xv[2 * s + 1].w) << 16);
    bx[s] = r.v;
  }

  __syncthreads();   // Ws-half staged

  // ---- phase 1: x * Ws (tiles 0..7), frags via ds_read_b128
  f32x4_t acc[8];
#pragma unroll
  for (int t = 0; t < 8; ++t) acc[t] = (f32x4_t){0.f, 0.f, 0.f, 0.f};
  const bf16x8_t* sWf = reinterpret_cast<const bf16x8_t*>(sW);
#pragma unroll
  for (int t = 0; t < 8; ++t)
#pragma unroll
    for (int s = 0; s < 4; ++s)
      acc[t] = __builtin_amdgcn_mfma_f32_16x16x32_bf16(
          sWf[(t * 4 + s) * 64 + lane], bx[s], acc[t], 0, 0, 0);

  __syncthreads();   // all waves done reading Ws-half
  // ---- stage Wn-half frag table
#pragma unroll
  for (int i = 0; i < 8; ++i) {
    const int c0 = i * 256 + wid * 64;
    stage16(ws + 32768 + (size_t)(c0 + lane) * 16, sW + (size_t)c0 * 16);
  }
  __syncthreads();   // Wn-half staged

  // ---- phase 2: mean * Wn into the same accumulators
#pragma unroll
  for (int t = 0; t < 8; ++t)
#pragma unroll
    for (int s = 0; s < 4; ++s)
      acc[t] = __builtin_amdgcn_mfma_f32_16x16x32_bf16(
          sWf[(t * 4 + s) * 64 + lane], bm[s], acc[t], 0, 0, 0);

  // ---- epilogue: + bias, relu, packed float4 stores direct to out
  const float* bias = reinterpret_cast<const float*>(ws + BIAS_OFF);
  float* op = out + (size_t)myrow * NF;
#pragma unroll
  for (int t = 0; t < 8; ++t) {
    const int c4 = t * 16 + q * 4;
    const float4 b = *reinterpret_cast<const float4*>(bias + c4);
    float4 o;
    o.x = fmaxf(acc[t][0] + b.x, 0.f);
    o.y = fmaxf(acc[t][1] + b.y, 0.f);
    o.z = fmaxf(acc[t][2] + b.z, 0.f);
    o.w = fmaxf(acc[t][3] + b.w, 0.f);
    *reinterpret_cast<float4*>(op + c4) = o;
  }
}

extern "C" void kernel_launch(void* const* d_in, const int* in_sizes, int n_in,
                              void* d_out, int out_size, void* d_ws, size_t ws_size,
                              hipStream_t stream) {
  const float* x     = (const float*)d_in[0];
  const int*   adj   = (const int*)d_in[1];
  const float* Wself = (const float*)d_in[2];
  const float* bself = (const float*)d_in[3];
  const float* Wnei  = (const float*)d_in[4];
  const float* bnei  = (const float*)d_in[5];
  float* out = (float*)d_out;
  unsigned char* ws = (unsigned char*)d_ws;

  hipLaunchKernelGGL(sage_prep, dim3(2065), dim3(256), 0, stream,
                     x, Wself, bself, Wnei, bnei, ws);
  hipLaunchKernelGGL(sage_fused, dim3(NBLK_G), dim3(256), 0, stream,
                     x, ws, adj, out);
}